// Round 5
// baseline (859.092 us; speedup 1.0000x reference)
//
#include <hip/hip_runtime.h>
#include <hip/hip_fp16.h>

// Sizes fixed by the reference problem.
#define HN 128
#define NN 20000
#define GG 32768
#define EE 1000000
#define NSEG (NN + GG)   // 52768
#define TE 128           // edges (or rows) per block tile

typedef _Float16 f16;
typedef __attribute__((ext_vector_type(8))) _Float16 f16x8;
typedef __attribute__((ext_vector_type(4))) float f32x4;

// XOR-swizzled LDS layout for a [TE][HN] f16 tile (row stride 256B).
__device__ __forceinline__ int swz_h(int row, int col) {
  int b = (row << 8) + (col << 1);
  b ^= (row & 7) << 4;
  return b >> 1;
}

// XOR-swizzled [128][64] f32 tile (row stride 256B), float-index result.
__device__ __forceinline__ int swz_f(int row, int lcol) {
  int b = (row << 8) + (lcol << 2);
  b ^= (row & 7) << 4;
  return b >> 2;
}

__device__ __forceinline__ float silu_f(float x) {
  return x / (1.0f + __expf(-x));
}

__device__ __forceinline__ f32x4 mfma16(f16x8 a, f16x8 b, f32x4 c) {
  return __builtin_amdgcn_mfma_f32_16x16x32_f16(a, b, c, 0, 0, 0);
}

// ---------------------------------------------------------------------------
// Pack f32 weights [K][128] into fp16 MFMA B-fragment order.
// ---------------------------------------------------------------------------
__global__ void pack_weights(const float* __restrict__ We2,
                             const float* __restrict__ Wm1,
                             const float* __restrict__ Wm2,
                             const float* __restrict__ Wu1,
                             const float* __restrict__ Wu2,
                             f16* __restrict__ dst) {
  const int wid = blockIdx.y;
  const float* src = (wid == 0) ? We2 : (wid == 1) ? Wm1 : (wid == 2) ? Wm2
                    : (wid == 3) ? Wu1 : Wu2;
  const int K   = (wid == 1) ? 256 : 128;
  const int off = (wid == 0) ? 0 : (wid == 1) ? 16384 : (wid == 2) ? 49152
                : (wid == 3) ? 65536 : 81920;
  int p = blockIdx.x * 256 + threadIdx.x;
  if (p >= K * HN) return;
  const int KS = K >> 5;
  int t   = p / (KS * 512);
  int rem = p - t * KS * 512;
  int s   = rem >> 9;
  int q   = rem & 511;
  int lane = q >> 3, e = q & 7;
  int k = s * 32 + ((lane >> 4) << 3) + e;
  int n = (t << 4) + (lane & 15);
  dst[off + p] = (f16)src[k * HN + n];
}

// Convert node_embedding to fp16 (row-major, same layout).
__global__ void conv_emb(const float* __restrict__ emb, f16* __restrict__ emb16) {
  int idx = blockIdx.x * 256 + threadIdx.x;
  int stride = gridDim.x * 256;
  for (int p = idx; p < NN * HN / 4; p += stride) {
    float4 v = *reinterpret_cast<const float4*>(emb + p * 4);
    f16 o[4] = {(f16)v.x, (f16)v.y, (f16)v.z, (f16)v.w};
    *reinterpret_cast<ulong1*>(emb16 + p * 4) = *reinterpret_cast<ulong1*>(o);
  }
}

// ---------------------------------------------------------------------------
// Destination histogram over grid ids (bin = j - NN).
// ---------------------------------------------------------------------------
__global__ void hist_kernel(const int* __restrict__ eidx, int* __restrict__ hist) {
  int e = blockIdx.x * 256 + threadIdx.x;
  if (e < EE) atomicAdd(&hist[eidx[EE + e] - NN], 1);
}

// Single-block exclusive scan of 32768 bins -> cursor.
__global__ __launch_bounds__(1024) void scan_kernel(const int* __restrict__ hist,
                                                    int* __restrict__ cursor) {
  __shared__ int sbuf[1024];
  int tid = threadIdx.x;
  int base = tid * 32;
  int v[32];
  int s = 0;
#pragma unroll
  for (int k = 0; k < 32; k++) { int t = hist[base + k]; v[k] = s; s += t; }
  int tot = s;
  sbuf[tid] = s;
  __syncthreads();
  for (int off = 1; off < 1024; off <<= 1) {
    int x = (tid >= off) ? sbuf[tid - off] : 0;
    __syncthreads();
    sbuf[tid] += x;
    __syncthreads();
  }
  int excl = sbuf[tid] - tot;
#pragma unroll
  for (int k = 0; k < 32; k++) cursor[base + k] = excl + v[k];
}

// Build destination-sorted (i, j) pairs.
__global__ void reorder_kernel(const int* __restrict__ eidx,
                               int* __restrict__ cursor, int2* __restrict__ sij) {
  int e = blockIdx.x * 256 + threadIdx.x;
  if (e < EE) {
    int j = eidx[EE + e];
    int p = atomicAdd(&cursor[j - NN], 1);
    sij[p] = make_int2(eidx[e], j);
  }
}

// ---------------------------------------------------------------------------
// Edge kernel over destination-sorted edges: gather -> h1 (VALU) -> GEMM1 ->
// GEMM2 -> GEMM3 -> segmented run-reduce scatter (j non-decreasing in block).
// ---------------------------------------------------------------------------
__global__ __launch_bounds__(256, 4) void edge_kernel(
    const f16* __restrict__ emb16, const float* __restrict__ npos,
    const float* __restrict__ gpos,
    const float* __restrict__ frames, const int* __restrict__ batch,
    const int2* __restrict__ sij,
    const float* __restrict__ We1, const float* __restrict__ be1,
    const f16* __restrict__ We2p, const float* __restrict__ be2,
    const f16* __restrict__ Wm1p, const float* __restrict__ bm1,
    const f16* __restrict__ Wm2p, const float* __restrict__ bm2,
    float* __restrict__ out) {
  __shared__ __align__(16) f16 A1[TE * HN];   // 32 KB, reused as f32 [128][64]
  __shared__ float sLR[TE * 3];
  __shared__ int sI[TE];
  __shared__ int sJ[TE];

  const int tid = threadIdx.x;
  const int ebase = blockIdx.x * TE;

  // Phase 0: gather sorted (i,j) + frame rotation
  if (tid < TE) {
    int p = ebase + tid;
    bool valid = p < EE;
    int2 ij = sij[valid ? p : 0];
    int i = ij.x;
    int g = ij.y - NN;
    float r0 = gpos[g * 3 + 0] - npos[i * 3 + 0];
    float r1 = gpos[g * 3 + 1] - npos[i * 3 + 1];
    float r2 = gpos[g * 3 + 2] - npos[i * 3 + 2];
    const float* F = frames + batch[i] * 9;
    sLR[tid * 3 + 0] = F[0] * r0 + F[1] * r1 + F[2] * r2;
    sLR[tid * 3 + 1] = F[3] * r0 + F[4] * r1 + F[5] * r2;
    sLR[tid * 3 + 2] = F[6] * r0 + F[7] * r1 + F[8] * r2;
    sI[tid] = i;
    sJ[tid] = valid ? ij.y : -1;
  }
  __syncthreads();

  // Phase 1: h1 = silu(local_rel @ We1 + be1)
  for (int idx = tid; idx < TE * HN; idx += 256) {
    int e = idx >> 7, h = idx & (HN - 1);
    float x = sLR[e * 3 + 0] * We1[h] + sLR[e * 3 + 1] * We1[HN + h] +
              sLR[e * 3 + 2] * We1[2 * HN + h] + be1[h];
    A1[swz_h(e, h)] = (f16)silu_f(x);
  }
  __syncthreads();

  const int lane = tid & 63;
  const int w = tid >> 6;
  const int lr_ = lane & 15;
  const int hi = lane >> 4;
  const int r0w = w * 32;

  f32x4 acc[2][8];

  // ---- GEMM1: pos_emb = h1 @ We2 + be2
  {
    f16x8 a[2][4];
#pragma unroll
    for (int mt = 0; mt < 2; mt++)
#pragma unroll
      for (int s = 0; s < 4; s++)
        a[mt][s] = *(const f16x8*)(A1 + swz_h(r0w + mt * 16 + lr_, s * 32 + hi * 8));
#pragma unroll
    for (int t = 0; t < 8; t++) {
      float bv = be2[t * 16 + lr_];
      acc[0][t] = (f32x4){bv, bv, bv, bv};
      acc[1][t] = (f32x4){bv, bv, bv, bv};
    }
#pragma unroll
    for (int t = 0; t < 8; t++)
#pragma unroll
      for (int s = 0; s < 4; s++) {
        f16x8 b = *(const f16x8*)(We2p + (size_t)((t * 4 + s) * 64 + lane) * 8);
        acc[0][t] = mfma16(a[0][s], b, acc[0][t]);
        acc[1][t] = mfma16(a[1][s], b, acc[1][t]);
      }
  }
  __syncthreads();
#pragma unroll
  for (int mt = 0; mt < 2; mt++)
#pragma unroll
    for (int t = 0; t < 8; t++)
#pragma unroll
      for (int r = 0; r < 4; r++)
        A1[swz_h(r0w + mt * 16 + hi * 4 + r, t * 16 + lr_)] = (f16)acc[mt][t][r];
  __syncthreads();

  // ---- GEMM2: mh = silu([emb_i | pos_emb] @ Wm1 + bm1)
  {
    f16x8 aq[2][4];
    f16x8 ae[2][4];
#pragma unroll
    for (int mt = 0; mt < 2; mt++) {
#pragma unroll
      for (int s = 0; s < 4; s++)
        aq[mt][s] = *(const f16x8*)(A1 + swz_h(r0w + mt * 16 + lr_, s * 32 + hi * 8));
      const f16* ep = emb16 + (size_t)sI[r0w + mt * 16 + lr_] * HN + hi * 8;
#pragma unroll
      for (int s = 0; s < 4; s++)
        ae[mt][s] = *(const f16x8*)(ep + s * 32);
    }
#pragma unroll
    for (int t = 0; t < 8; t++) {
      float bv = bm1[t * 16 + lr_];
      acc[0][t] = (f32x4){bv, bv, bv, bv};
      acc[1][t] = (f32x4){bv, bv, bv, bv};
    }
#pragma unroll
    for (int t = 0; t < 8; t++)
#pragma unroll
      for (int s = 0; s < 8; s++) {
        f16x8 b = *(const f16x8*)(Wm1p + (size_t)((t * 8 + s) * 64 + lane) * 8);
        f16x8 a0 = (s < 4) ? ae[0][s & 3] : aq[0][s & 3];
        f16x8 a1 = (s < 4) ? ae[1][s & 3] : aq[1][s & 3];
        acc[0][t] = mfma16(a0, b, acc[0][t]);
        acc[1][t] = mfma16(a1, b, acc[1][t]);
      }
  }
  __syncthreads();
#pragma unroll
  for (int mt = 0; mt < 2; mt++)
#pragma unroll
    for (int t = 0; t < 8; t++)
#pragma unroll
      for (int r = 0; r < 4; r++)
        A1[swz_h(r0w + mt * 16 + hi * 4 + r, t * 16 + lr_)] = (f16)silu_f(acc[mt][t][r]);
  __syncthreads();

  // ---- GEMM3: msg = mh @ Wm2 + bm2
  {
    f16x8 a[2][4];
#pragma unroll
    for (int mt = 0; mt < 2; mt++)
#pragma unroll
      for (int s = 0; s < 4; s++)
        a[mt][s] = *(const f16x8*)(A1 + swz_h(r0w + mt * 16 + lr_, s * 32 + hi * 8));
#pragma unroll
    for (int t = 0; t < 8; t++) {
      float bv = bm2[t * 16 + lr_];
      acc[0][t] = (f32x4){bv, bv, bv, bv};
      acc[1][t] = (f32x4){bv, bv, bv, bv};
    }
#pragma unroll
    for (int t = 0; t < 8; t++)
#pragma unroll
      for (int s = 0; s < 4; s++) {
        f16x8 b = *(const f16x8*)(Wm2p + (size_t)((t * 4 + s) * 64 + lane) * 8);
        acc[0][t] = mfma16(a[0][s], b, acc[0][t]);
        acc[1][t] = mfma16(a[1][s], b, acc[1][t]);
      }
  }

  // ---- Segmented scatter: two 64-col halves through the 32 KB LDS tile.
  float* M = (float*)A1;
  const int c  = tid & 63;   // local column
  const int g  = tid >> 6;   // row group (32 rows each)
#pragma unroll
  for (int half = 0; half < 2; half++) {
    __syncthreads();   // previous phase's LDS reads (or prior half) done
#pragma unroll
    for (int mt = 0; mt < 2; mt++)
#pragma unroll
      for (int tq = 0; tq < 4; tq++)
#pragma unroll
        for (int r = 0; r < 4; r++)
          M[swz_f(r0w + mt * 16 + hi * 4 + r, tq * 16 + lr_)] =
              acc[mt][half * 4 + tq][r];
    __syncthreads();
    // Walk 32 rows (rotated start so the 4 groups hit distinct banks),
    // merging runs of equal j; one atomicAdd per run.
    float run = 0.0f;
    int jcur = -2;
    for (int k = 0; k < 32; k++) {
      int row = g * 32 + ((k + g) & 31);
      int jr = sJ[row];
      float v = M[swz_f(row, c)];
      if (jr != jcur) {
        if (jcur >= 0) atomicAdd(&out[(size_t)jcur * HN + half * 64 + c], run);
        run = 0.0f;
        jcur = jr;
      }
      if (jr >= 0) run += v;
    }
    if (jcur >= 0) atomicAdd(&out[(size_t)jcur * HN + half * 64 + c], run);
  }
}

// ---------------------------------------------------------------------------
// Finalize: mean = out/max(cnt,1); out = silu(mean@Wu1+bu1)@Wu2+bu2, in place.
// ---------------------------------------------------------------------------
__global__ __launch_bounds__(256, 4) void finalize_kernel(
    float* __restrict__ out, const int* __restrict__ hist,
    const f16* __restrict__ Wu1p, const float* __restrict__ bu1,
    const f16* __restrict__ Wu2p, const float* __restrict__ bu2) {
  __shared__ __align__(16) f16 A1[TE * HN];
  const int tid = threadIdx.x;
  const int rbase = blockIdx.x * TE;

  for (int idx = tid; idx < TE * HN; idx += 256) {
    int e = idx >> 7, h = idx & (HN - 1);
    int row = rbase + e;
    float v = 0.0f;
    if (row < NSEG) {
      float cv = (row >= NN) ? (float)hist[row - NN] : 0.0f;
      v = out[(size_t)row * HN + h] / fmaxf(cv, 1.0f);
    }
    A1[swz_h(e, h)] = (f16)v;
  }
  __syncthreads();

  const int lane = tid & 63;
  const int w = tid >> 6;
  const int lr_ = lane & 15;
  const int hi = lane >> 4;
  const int r0w = w * 32;

  f32x4 acc[2][8];

  // GEMM A: hidden = silu(mean @ Wu1 + bu1)
  {
    f16x8 a[2][4];
#pragma unroll
    for (int mt = 0; mt < 2; mt++)
#pragma unroll
      for (int s = 0; s < 4; s++)
        a[mt][s] = *(const f16x8*)(A1 + swz_h(r0w + mt * 16 + lr_, s * 32 + hi * 8));
#pragma unroll
    for (int t = 0; t < 8; t++) {
      float bv = bu1[t * 16 + lr_];
      acc[0][t] = (f32x4){bv, bv, bv, bv};
      acc[1][t] = (f32x4){bv, bv, bv, bv};
    }
#pragma unroll
    for (int t = 0; t < 8; t++)
#pragma unroll
      for (int s = 0; s < 4; s++) {
        f16x8 b = *(const f16x8*)(Wu1p + (size_t)((t * 4 + s) * 64 + lane) * 8);
        acc[0][t] = mfma16(a[0][s], b, acc[0][t]);
        acc[1][t] = mfma16(a[1][s], b, acc[1][t]);
      }
  }
  __syncthreads();
#pragma unroll
  for (int mt = 0; mt < 2; mt++)
#pragma unroll
    for (int t = 0; t < 8; t++)
#pragma unroll
      for (int r = 0; r < 4; r++)
        A1[swz_h(r0w + mt * 16 + hi * 4 + r, t * 16 + lr_)] = (f16)silu_f(acc[mt][t][r]);
  __syncthreads();

  // GEMM B: out = hidden @ Wu2 + bu2
  {
    f16x8 a[2][4];
#pragma unroll
    for (int mt = 0; mt < 2; mt++)
#pragma unroll
      for (int s = 0; s < 4; s++)
        a[mt][s] = *(const f16x8*)(A1 + swz_h(r0w + mt * 16 + lr_, s * 32 + hi * 8));
#pragma unroll
    for (int t = 0; t < 8; t++) {
      float bv = bu2[t * 16 + lr_];
      acc[0][t] = (f32x4){bv, bv, bv, bv};
      acc[1][t] = (f32x4){bv, bv, bv, bv};
    }
#pragma unroll
    for (int t = 0; t < 8; t++)
#pragma unroll
      for (int s = 0; s < 4; s++) {
        f16x8 b = *(const f16x8*)(Wu2p + (size_t)((t * 4 + s) * 64 + lane) * 8);
        acc[0][t] = mfma16(a[0][s], b, acc[0][t]);
        acc[1][t] = mfma16(a[1][s], b, acc[1][t]);
      }
  }
#pragma unroll
  for (int mt = 0; mt < 2; mt++)
#pragma unroll
    for (int t = 0; t < 8; t++)
#pragma unroll
      for (int r = 0; r < 4; r++) {
        int row = rbase + r0w + mt * 16 + hi * 4 + r;
        if (row < NSEG) out[(size_t)row * HN + t * 16 + lr_] = acc[mt][t][r];
      }
}

extern "C" void kernel_launch(void* const* d_in, const int* in_sizes, int n_in,
                              void* d_out, int out_size, void* d_ws, size_t ws_size,
                              hipStream_t stream) {
  const float* emb    = (const float*)d_in[0];
  const float* npos   = (const float*)d_in[1];
  const float* gpos   = (const float*)d_in[2];
  const int*   eidx   = (const int*)d_in[3];
  const float* frames = (const float*)d_in[4];
  const int*   batch  = (const int*)d_in[5];
  const float* We1 = (const float*)d_in[6];
  const float* be1 = (const float*)d_in[7];
  const float* We2 = (const float*)d_in[8];
  const float* be2 = (const float*)d_in[9];
  const float* Wm1 = (const float*)d_in[10];
  const float* bm1 = (const float*)d_in[11];
  const float* Wm2 = (const float*)d_in[12];
  const float* bm2 = (const float*)d_in[13];
  const float* Wu1 = (const float*)d_in[14];
  const float* bu1 = (const float*)d_in[15];
  const float* Wu2 = (const float*)d_in[16];
  const float* bu2 = (const float*)d_in[17];

  float* out  = (float*)d_out;
  int* hist   = (int*)d_ws;                              // 128 KB @ 0
  int* cursor = (int*)((char*)d_ws + 131072);            // 128 KB
  int2* sij   = (int2*)((char*)d_ws + 262144);           // 8 MB sorted (i,j)
  f16* emb16  = (f16*)((char*)d_ws + 8262144);           // 5 MB fp16 embeddings
  f16* wp     = (f16*)((char*)d_ws + 13382144);          // 192 KB packed weights
  f16* We2p   = wp;
  f16* Wm1p   = wp + 16384;
  f16* Wm2p   = wp + 49152;
  f16* Wu1p   = wp + 65536;
  f16* Wu2p   = wp + 81920;

  hipMemsetAsync(d_out, 0, (size_t)NSEG * HN * sizeof(float), stream);
  hipMemsetAsync(hist, 0, (size_t)GG * sizeof(int), stream);

  pack_weights<<<dim3(128, 5), 256, 0, stream>>>(We2, Wm1, Wm2, Wu1, Wu2, wp);
  conv_emb<<<640, 256, 0, stream>>>(emb, emb16);

  int eb = (EE + 255) / 256;
  hist_kernel<<<eb, 256, 0, stream>>>(eidx, hist);
  scan_kernel<<<1, 1024, 0, stream>>>(hist, cursor);
  reorder_kernel<<<eb, 256, 0, stream>>>(eidx, cursor, sij);

  int eblocks = (EE + TE - 1) / TE;                // 7813
  edge_kernel<<<eblocks, 256, 0, stream>>>(
      emb16, npos, gpos, frames, batch, sij, We1, be1, We2p, be2,
      Wm1p, bm1, Wm2p, bm2, out);

  int fblocks = (NSEG + TE - 1) / TE;              // 413
  finalize_kernel<<<fblocks, 256, 0, stream>>>(out, hist, Wu1p, bu1, Wu2p, bu2);
}

// Round 13
// 485.140 us; speedup vs baseline: 1.7708x; 1.7708x over previous
//
#include <hip/hip_runtime.h>
#include <hip/hip_fp16.h>

// Sizes fixed by the reference problem.
#define HN 128
#define NN 20000
#define GG 32768
#define EE 1000000
#define NSEG (NN + GG)   // 52768
#define TE 128           // rows per block tile

typedef _Float16 f16;
typedef __attribute__((ext_vector_type(8))) _Float16 f16x8;
typedef __attribute__((ext_vector_type(4))) float f32x4;

// XOR-swizzled LDS layout for a [TE][HN] f16 tile (row stride 256B).
__device__ __forceinline__ int swz_h(int row, int col) {
  int b = (row << 8) + (col << 1);
  b ^= (row & 7) << 4;
  return b >> 1;
}

// XOR-swizzled [128][64] f32 tile (row stride 256B), float-index result.
__device__ __forceinline__ int swz_f(int row, int lcol) {
  int b = (row << 8) + (lcol << 2);
  b ^= (row & 7) << 4;
  return b >> 2;
}

__device__ __forceinline__ float silu_f(float x) {
  return x / (1.0f + __expf(-x));
}

__device__ __forceinline__ f32x4 mfma16(f16x8 a, f16x8 b, f32x4 c) {
  return __builtin_amdgcn_mfma_f32_16x16x32_f16(a, b, c, 0, 0, 0);
}

// ---------------------------------------------------------------------------
// Pack f32 weights [K][128] into fp16 MFMA B-fragment order:
//   idx = ((t*KS + s)*64 + lane)*8 + e  ->  W[k][n],
//   k = s*32 + (lane>>4)*8 + e, n = t*16 + (lane&15).
// Packs Wm1 (K=256) @0, Wm2 @32768, Wu1 @49152, Wu2 @65536 (f16 units).
// ---------------------------------------------------------------------------
__global__ void pack_weights(const float* __restrict__ Wm1,
                             const float* __restrict__ Wm2,
                             const float* __restrict__ Wu1,
                             const float* __restrict__ Wu2,
                             f16* __restrict__ dst) {
  int p = blockIdx.x * 256 + threadIdx.x;  // 0..81919
  if (p >= 81920) return;
  const float* src; int K, off, q;
  if (p < 32768)      { src = Wm1; K = 256; off = 0;     q = p; }
  else if (p < 49152) { src = Wm2; K = 128; off = 32768; q = p - 32768; }
  else if (p < 65536) { src = Wu1; K = 128; off = 49152; q = p - 49152; }
  else                { src = Wu2; K = 128; off = 65536; q = p - 65536; }
  int KS = K >> 5;
  int t   = q / (KS * 512);
  int rem = q - t * KS * 512;
  int s   = rem >> 9;
  int qq  = rem & 511;
  int lane = qq >> 3, e = qq & 7;
  int k = s * 32 + ((lane >> 4) << 3) + e;
  int n = (t << 4) + (lane & 15);
  dst[off + q] = (f16)src[k * HN + n];
}

// ---------------------------------------------------------------------------
// Wc = We2 @ Wm1_bot (written directly in packed B-frag layout, KS=4),
// bvec = bm1 + be2 @ Wm1_bot, cvec = silu(bu1) @ Wu2 + bu2.
// ---------------------------------------------------------------------------
__global__ void wc_vec_kernel(const float* __restrict__ We2,
                              const float* __restrict__ Wm1,
                              const float* __restrict__ be2,
                              const float* __restrict__ bm1,
                              const float* __restrict__ bu1,
                              const float* __restrict__ Wu2,
                              const float* __restrict__ bu2,
                              f16* __restrict__ Wcp,
                              float* __restrict__ bvec,
                              float* __restrict__ cvec) {
  if (blockIdx.x < 64) {
    int o = blockIdx.x * 256 + threadIdx.x;  // 16384 outputs
    int k = o >> 7, n = o & 127;
    float s = 0.0f;
    for (int m = 0; m < 128; m++)
      s += We2[k * HN + m] * Wm1[(128 + m) * HN + n];
    int t = n >> 4, sg = k >> 5;
    int lane = (((k >> 3) & 3) << 4) | (n & 15);
    int e = k & 7;
    Wcp[((size_t)(t * 4 + sg) * 64 + lane) * 8 + e] = (f16)s;
  } else {
    int tid = threadIdx.x;
    if (tid < 128) {
      float s = bm1[tid];
      for (int m = 0; m < 128; m++) s += be2[m] * Wm1[(128 + m) * HN + tid];
      bvec[tid] = s;
    } else {
      int n = tid - 128;
      float s = bu2[n];
      for (int m = 0; m < 128; m++) s += silu_f(bu1[m]) * Wu2[m * HN + n];
      cvec[n] = s;
    }
  }
}

// ---------------------------------------------------------------------------
// Ynode[i] = emb[i] @ Wm1_top + bvec  (f16 out, row-major [NN][128]).
// Uses packed Wm1p with KS=8, s=0..3 (k<128 half).
// ---------------------------------------------------------------------------
__global__ __launch_bounds__(256, 2) void ynode_kernel(
    const float* __restrict__ emb, const f16* __restrict__ Wm1p,
    const float* __restrict__ bvec, f16* __restrict__ Ynode) {
  __shared__ __align__(16) f16 A1[TE * HN];
  const int tid = threadIdx.x;
  const int rbase = blockIdx.x * TE;

  for (int idx = tid; idx < TE * HN; idx += 256) {
    int e = idx >> 7, h = idx & (HN - 1);
    int row = rbase + e;
    float v = (row < NN) ? emb[(size_t)row * HN + h] : 0.0f;
    A1[swz_h(e, h)] = (f16)v;
  }
  __syncthreads();

  const int lane = tid & 63;
  const int w = tid >> 6;
  const int lr_ = lane & 15;
  const int hi = lane >> 4;
  const int r0w = w * 32;

  f16x8 a[2][4];
#pragma unroll
  for (int mt = 0; mt < 2; mt++)
#pragma unroll
    for (int s = 0; s < 4; s++)
      a[mt][s] = *(const f16x8*)(A1 + swz_h(r0w + mt * 16 + lr_, s * 32 + hi * 8));

  f32x4 acc[2][8];
#pragma unroll
  for (int t = 0; t < 8; t++) {
    float bv = bvec[t * 16 + lr_];
    acc[0][t] = (f32x4){bv, bv, bv, bv};
    acc[1][t] = (f32x4){bv, bv, bv, bv};
  }
#pragma unroll
  for (int t = 0; t < 8; t++)
#pragma unroll
    for (int s = 0; s < 4; s++) {  // top half of K=256 pack: s in 0..3
      f16x8 b = *(const f16x8*)(Wm1p + (size_t)((t * 8 + s) * 64 + lane) * 8);
      acc[0][t] = mfma16(a[0][s], b, acc[0][t]);
      acc[1][t] = mfma16(a[1][s], b, acc[1][t]);
    }
#pragma unroll
  for (int mt = 0; mt < 2; mt++)
#pragma unroll
    for (int t = 0; t < 8; t++)
#pragma unroll
      for (int r = 0; r < 4; r++) {
        int row = rbase + r0w + mt * 16 + hi * 4 + r;
        if (row < NN)
          Ynode[(size_t)row * HN + t * 16 + lr_] = (f16)acc[mt][t][r];
      }
}

// ---------------------------------------------------------------------------
// Destination histogram over grid ids (bin = j - NN).
// ---------------------------------------------------------------------------
__global__ void hist_kernel(const int* __restrict__ eidx, int* __restrict__ hist) {
  int e = blockIdx.x * 256 + threadIdx.x;
  if (e < EE) atomicAdd(&hist[eidx[EE + e] - NN], 1);
}

// Single-block exclusive scan of 32768 bins -> cursor.
__global__ __launch_bounds__(1024) void scan_kernel(const int* __restrict__ hist,
                                                    int* __restrict__ cursor) {
  __shared__ int sbuf[1024];
  int tid = threadIdx.x;
  int base = tid * 32;
  int v[32];
  int s = 0;
#pragma unroll
  for (int k = 0; k < 32; k++) { int t = hist[base + k]; v[k] = s; s += t; }
  int tot = s;
  sbuf[tid] = s;
  __syncthreads();
  for (int off = 1; off < 1024; off <<= 1) {
    int x = (tid >= off) ? sbuf[tid - off] : 0;
    __syncthreads();
    sbuf[tid] += x;
    __syncthreads();
  }
  int excl = sbuf[tid] - tot;
#pragma unroll
  for (int k = 0; k < 32; k++) cursor[base + k] = excl + v[k];
}

// Build destination-sorted (i, j) pairs.
__global__ void reorder_kernel(const int* __restrict__ eidx,
                               int* __restrict__ cursor, int2* __restrict__ sij) {
  int e = blockIdx.x * 256 + threadIdx.x;
  if (e < EE) {
    int j = eidx[EE + e];
    int p = atomicAdd(&cursor[j - NN], 1);
    sij[p] = make_int2(eidx[e], j);
  }
}

// ---------------------------------------------------------------------------
// Edge kernel (destination-sorted): gather+rotate -> h1 in A-frag registers
// -> ONE GEMM (h1 @ Wc) -> mh = silu(z + Ynode[i]) fused into the segmented
// run-merge scatter (two 64-col halves through a 32 KB LDS transpose tile).
// ---------------------------------------------------------------------------
__global__ __launch_bounds__(256, 3) void edge_kernel(
    const f16* __restrict__ Ynode, const float* __restrict__ npos,
    const float* __restrict__ gpos, const float* __restrict__ frames,
    const int* __restrict__ batch, const int2* __restrict__ sij,
    const float* __restrict__ We1, const float* __restrict__ be1,
    const f16* __restrict__ Wcp, float* __restrict__ out) {
  __shared__ __align__(16) float M[TE * 64];   // 32 KB scatter staging
  __shared__ float sW[4 * HN];                 // We1 rows (3x128) + be1
  __shared__ float sLR[TE * 3];
  __shared__ int sI[TE];
  __shared__ int sJ[TE];

  const int tid = threadIdx.x;
  const int ebase = blockIdx.x * TE;

  for (int k = tid; k < 4 * HN; k += 256)
    sW[k] = (k < 3 * HN) ? We1[k] : be1[k - 3 * HN];

  if (tid < TE) {
    int p = ebase + tid;
    bool valid = p < EE;
    int2 ij = sij[valid ? p : 0];
    int i = ij.x;
    int g = ij.y - NN;
    float r0 = gpos[g * 3 + 0] - npos[i * 3 + 0];
    float r1 = gpos[g * 3 + 1] - npos[i * 3 + 1];
    float r2 = gpos[g * 3 + 2] - npos[i * 3 + 2];
    const float* F = frames + batch[i] * 9;
    sLR[tid * 3 + 0] = F[0] * r0 + F[1] * r1 + F[2] * r2;
    sLR[tid * 3 + 1] = F[3] * r0 + F[4] * r1 + F[5] * r2;
    sLR[tid * 3 + 2] = F[6] * r0 + F[7] * r1 + F[8] * r2;
    sI[tid] = i;
    sJ[tid] = valid ? ij.y : -1;
  }
  __syncthreads();

  const int lane = tid & 63;
  const int w = tid >> 6;
  const int lr_ = lane & 15;
  const int hi = lane >> 4;
  const int r0w = w * 32;

  // h1 computed directly in A-fragment registers: row=lr_, k=s*32+hi*8+e.
  f16x8 afr[2][4];
#pragma unroll
  for (int mt = 0; mt < 2; mt++) {
    int row = r0w + mt * 16 + lr_;
    float l0 = sLR[row * 3 + 0], l1 = sLR[row * 3 + 1], l2 = sLR[row * 3 + 2];
#pragma unroll
    for (int s = 0; s < 4; s++) {
      f16x8 a;
#pragma unroll
      for (int e = 0; e < 8; e++) {
        int k = s * 32 + hi * 8 + e;
        float x = l0 * sW[k] + l1 * sW[HN + k] + l2 * sW[2 * HN + k] + sW[3 * HN + k];
        a[e] = (f16)silu_f(x);
      }
      afr[mt][s] = a;
    }
  }

  f32x4 acc[2][8];
#pragma unroll
  for (int mt = 0; mt < 2; mt++)
#pragma unroll
    for (int t = 0; t < 8; t++) acc[mt][t] = (f32x4){0.f, 0.f, 0.f, 0.f};
#pragma unroll
  for (int t = 0; t < 8; t++)
#pragma unroll
    for (int s = 0; s < 4; s++) {
      f16x8 b = *(const f16x8*)(Wcp + (size_t)((t * 4 + s) * 64 + lane) * 8);
      acc[0][t] = mfma16(afr[0][s], b, acc[0][t]);
      acc[1][t] = mfma16(afr[1][s], b, acc[1][t]);
    }

  // Segmented scatter: per half, transpose z through LDS, fuse silu(z+Y),
  // run-merge equal-j rows (sorted => ascending), one atomic per run.
#pragma unroll
  for (int half = 0; half < 2; half++) {
    if (half) __syncthreads();
#pragma unroll
    for (int mt = 0; mt < 2; mt++)
#pragma unroll
      for (int tq = 0; tq < 4; tq++)
#pragma unroll
        for (int r = 0; r < 4; r++)
          M[swz_f(r0w + mt * 16 + hi * 4 + r, tq * 16 + lr_)] =
              acc[mt][half * 4 + tq][r];
    __syncthreads();
    const int colg = half * 64 + lane;
    f16 yv[32];
#pragma unroll
    for (int k = 0; k < 32; k++)
      yv[k] = Ynode[(size_t)sI[r0w + k] * HN + colg];
    float run = 0.0f;
    int jcur = -2;
#pragma unroll
    for (int k = 0; k < 32; k++) {
      int row = r0w + k;
      int jr = sJ[row];
      float v = silu_f(M[swz_f(row, lane)] + (float)yv[k]);
      if (jr != jcur) {
        if (jcur >= 0) atomicAdd(&out[(size_t)jcur * HN + colg], run);
        run = 0.0f;
        jcur = jr;
      }
      if (jr >= 0) run += v;
    }
    if (jcur >= 0) atomicAdd(&out[(size_t)jcur * HN + colg], run);
  }
}

// ---------------------------------------------------------------------------
// Finalize (grid rows only): mean_mh = seg_sum/max(cnt,1);
// x = mean_mh@Wm2 + bm2*(cnt>0); out = silu(x@Wu1+bu1)@Wu2+bu2, in place.
// ---------------------------------------------------------------------------
__global__ __launch_bounds__(256, 2) void finalize_kernel(
    float* __restrict__ out, const int* __restrict__ hist,
    const f16* __restrict__ Wm2p, const float* __restrict__ bm2,
    const f16* __restrict__ Wu1p, const float* __restrict__ bu1,
    const f16* __restrict__ Wu2p, const float* __restrict__ bu2) {
  __shared__ __align__(16) f16 A1[TE * HN];
  __shared__ float sb[TE];   // per-row (cnt>0) flag
  const int tid = threadIdx.x;
  const int rbase = NN + blockIdx.x * TE;   // 256 blocks cover GG exactly

  for (int idx = tid; idx < TE * HN; idx += 256) {
    int e = idx >> 7, h = idx & (HN - 1);
    int c = hist[rbase + e - NN];
    float v = out[(size_t)(rbase + e) * HN + h] / fmaxf((float)c, 1.0f);
    A1[swz_h(e, h)] = (f16)v;
    if (h == 0) sb[e] = (c > 0) ? 1.0f : 0.0f;
  }
  __syncthreads();

  const int lane = tid & 63;
  const int w = tid >> 6;
  const int lr_ = lane & 15;
  const int hi = lane >> 4;
  const int r0w = w * 32;

  f32x4 acc[2][8];

  // G1: x = mean_mh @ Wm2 + bm2*flag
  {
    f16x8 a[2][4];
#pragma unroll
    for (int mt = 0; mt < 2; mt++)
#pragma unroll
      for (int s = 0; s < 4; s++)
        a[mt][s] = *(const f16x8*)(A1 + swz_h(r0w + mt * 16 + lr_, s * 32 + hi * 8));
#pragma unroll
    for (int mt = 0; mt < 2; mt++)
#pragma unroll
      for (int t = 0; t < 8; t++) {
        float bb = bm2[t * 16 + lr_];
        f32x4 c;
#pragma unroll
        for (int r = 0; r < 4; r++) c[r] = bb * sb[r0w + mt * 16 + hi * 4 + r];
        acc[mt][t] = c;
      }
#pragma unroll
    for (int t = 0; t < 8; t++)
#pragma unroll
      for (int s = 0; s < 4; s++) {
        f16x8 b = *(const f16x8*)(Wm2p + (size_t)((t * 4 + s) * 64 + lane) * 8);
        acc[0][t] = mfma16(a[0][s], b, acc[0][t]);
        acc[1][t] = mfma16(a[1][s], b, acc[1][t]);
      }
  }
  __syncthreads();
#pragma unroll
  for (int mt = 0; mt < 2; mt++)
#pragma unroll
    for (int t = 0; t < 8; t++)
#pragma unroll
      for (int r = 0; r < 4; r++)
        A1[swz_h(r0w + mt * 16 + hi * 4 + r, t * 16 + lr_)] = (f16)acc[mt][t][r];
  __syncthreads();

  // G2: h = silu(x @ Wu1 + bu1)
  {
    f16x8 a[2][4];
#pragma unroll
    for (int mt = 0; mt < 2; mt++)
#pragma unroll
      for (int s = 0; s < 4; s++)
        a[mt][s] = *(const f16x8*)(A1 + swz_h(r0w + mt * 16 + lr_, s * 32 + hi * 8));
#pragma unroll
    for (int t = 0; t < 8; t++) {
      float bv = bu1[t * 16 + lr_];
      acc[0][t] = (f32x4){bv, bv, bv, bv};
      acc[1][t] = (f32x4){bv, bv, bv, bv};
    }
#pragma unroll
    for (int t = 0; t < 8; t++)
#pragma unroll
      for (int s = 0; s < 4; s++) {
        f16x8 b = *(const f16x8*)(Wu1p + (size_t)((t * 4 + s) * 64 + lane) * 8);
        acc[0][t] = mfma16(a[0][s], b, acc[0][t]);
        acc[1][t] = mfma16(a[1][s], b, acc[1][t]);
      }
  }
  __syncthreads();
#pragma unroll
  for (int mt = 0; mt < 2; mt++)
#pragma unroll
    for (int t = 0; t < 8; t++)
#pragma unroll
      for (int r = 0; r < 4; r++)
        A1[swz_h(r0w + mt * 16 + hi * 4 + r, t * 16 + lr_)] = (f16)silu_f(acc[mt][t][r]);
  __syncthreads();

  // G3: out = h @ Wu2 + bu2
  {
    f16x8 a[2][4];
#pragma unroll
    for (int mt = 0; mt < 2; mt++)
#pragma unroll
      for (int s = 0; s < 4; s++)
        a[mt][s] = *(const f16x8*)(A1 + swz_h(r0w + mt * 16 + lr_, s * 32 + hi * 8));
#pragma unroll
    for (int t = 0; t < 8; t++) {
      float bv = bu2[t * 16 + lr_];
      acc[0][t] = (f32x4){bv, bv, bv, bv};
      acc[1][t] = (f32x4){bv, bv, bv, bv};
    }
#pragma unroll
    for (int t = 0; t < 8; t++)
#pragma unroll
      for (int s = 0; s < 4; s++) {
        f16x8 b = *(const f16x8*)(Wu2p + (size_t)((t * 4 + s) * 64 + lane) * 8);
        acc[0][t] = mfma16(a[0][s], b, acc[0][t]);
        acc[1][t] = mfma16(a[1][s], b, acc[1][t]);
      }
  }
#pragma unroll
  for (int mt = 0; mt < 2; mt++)
#pragma unroll
    for (int t = 0; t < 8; t++)
#pragma unroll
      for (int r = 0; r < 4; r++) {
        int row = rbase + r0w + mt * 16 + hi * 4 + r;
        out[(size_t)row * HN + t * 16 + lr_] = acc[mt][t][r];
      }
}

// Output rows [0, NN) all equal cvec = silu(bu1)@Wu2+bu2 (mean is 0 there).
__global__ void constfill_kernel(const float* __restrict__ cvec,
                                 float* __restrict__ out) {
  int i = blockIdx.x * 256 + threadIdx.x;   // over NN*HN/4 float4s
  if (i < NN * HN / 4) {
    float4 v = reinterpret_cast<const float4*>(cvec)[i & 31];
    reinterpret_cast<float4*>(out)[i] = v;
  }
}

extern "C" void kernel_launch(void* const* d_in, const int* in_sizes, int n_in,
                              void* d_out, int out_size, void* d_ws, size_t ws_size,
                              hipStream_t stream) {
  const float* emb    = (const float*)d_in[0];
  const float* npos   = (const float*)d_in[1];
  const float* gpos   = (const float*)d_in[2];
  const int*   eidx   = (const int*)d_in[3];
  const float* frames = (const float*)d_in[4];
  const int*   batch  = (const int*)d_in[5];
  const float* We1 = (const float*)d_in[6];
  const float* be1 = (const float*)d_in[7];
  const float* We2 = (const float*)d_in[8];
  const float* be2 = (const float*)d_in[9];
  const float* Wm1 = (const float*)d_in[10];
  const float* bm1 = (const float*)d_in[11];
  const float* Wm2 = (const float*)d_in[12];
  const float* bm2 = (const float*)d_in[13];
  const float* Wu1 = (const float*)d_in[14];
  const float* bu1 = (const float*)d_in[15];
  const float* Wu2 = (const float*)d_in[16];
  const float* bu2 = (const float*)d_in[17];

  float* out  = (float*)d_out;
  char* ws    = (char*)d_ws;
  int* hist   = (int*)ws;                        // 128 KB @ 0
  int* cursor = (int*)(ws + 131072);             // 128 KB
  f16* wp     = (f16*)(ws + 262144);             // 160 KB packed weights
  f16* Wm1p   = wp;                              // KS=8
  f16* Wm2p   = wp + 32768;
  f16* Wu1p   = wp + 49152;
  f16* Wu2p   = wp + 65536;
  f16* Wcp    = (f16*)(ws + 425984);             // 32 KB
  float* bvec = (float*)(ws + 458752);           // 512 B
  float* cvec = (float*)(ws + 459264);           // 512 B
  int2* sij   = (int2*)(ws + 524288);            // 8 MB sorted (i,j)
  f16* Ynode  = (f16*)(ws + 8524288);            // 5 MB

  // Zero only the grid-row region (edge scatter targets) + histogram.
  hipMemsetAsync(out + (size_t)NN * HN, 0, (size_t)GG * HN * sizeof(float), stream);
  hipMemsetAsync(hist, 0, (size_t)GG * sizeof(int), stream);

  pack_weights<<<320, 256, 0, stream>>>(Wm1, Wm2, Wu1, Wu2, wp);
  wc_vec_kernel<<<65, 256, 0, stream>>>(We2, Wm1, be2, bm1, bu1, Wu2, bu2,
                                        Wcp, bvec, cvec);
  ynode_kernel<<<(NN + TE - 1) / TE, 256, 0, stream>>>(emb, Wm1p, bvec, Ynode);

  int eb = (EE + 255) / 256;
  hist_kernel<<<eb, 256, 0, stream>>>(eidx, hist);
  scan_kernel<<<1, 1024, 0, stream>>>(hist, cursor);
  reorder_kernel<<<eb, 256, 0, stream>>>(eidx, cursor, sij);

  int eblocks = (EE + TE - 1) / TE;              // 7813
  edge_kernel<<<eblocks, 256, 0, stream>>>(
      Ynode, npos, gpos, frames, batch, sij, We1, be1, Wcp, out);

  finalize_kernel<<<GG / TE, 256, 0, stream>>>(out, hist, Wm2p, bm2,
                                               Wu1p, bu1, Wu2p, bu2);
  constfill_kernel<<<(NN * HN / 4 + 255) / 256, 256, 0, stream>>>(cvec, out);
}

// Round 14
// 409.197 us; speedup vs baseline: 2.0995x; 1.1856x over previous
//
#include <hip/hip_runtime.h>
#include <hip/hip_fp16.h>

// Sizes fixed by the reference problem.
#define HN 128
#define NN 20000
#define GG 32768
#define EE 1000000
#define NSEG (NN + GG)   // 52768
#define TE 128           // rows per block tile

typedef _Float16 f16;
typedef __attribute__((ext_vector_type(8))) _Float16 f16x8;
typedef __attribute__((ext_vector_type(4))) float f32x4;

// XOR-swizzled LDS layout for a [TE][HN] f16 tile (row stride 256B).
__device__ __forceinline__ int swz_h(int row, int col) {
  int b = (row << 8) + (col << 1);
  b ^= (row & 7) << 4;
  return b >> 1;
}

// XOR-swizzled [128][64] f32 tile (row stride 256B), float-index result.
__device__ __forceinline__ int swz_f(int row, int lcol) {
  int b = (row << 8) + (lcol << 2);
  b ^= (row & 7) << 4;
  return b >> 2;
}

// Fast silu: v_rcp (1 op) instead of precise fdiv (~7 ops). rel err ~1e-7,
// far below f16 storage eps (4.9e-4) and the 7.85e-3 threshold.
__device__ __forceinline__ float silu_f(float x) {
  float d = 1.0f + __expf(-x);
  return x * __builtin_amdgcn_rcpf(d);
}

__device__ __forceinline__ f32x4 mfma16(f16x8 a, f16x8 b, f32x4 c) {
  return __builtin_amdgcn_mfma_f32_16x16x32_f16(a, b, c, 0, 0, 0);
}

// ---------------------------------------------------------------------------
// Fused prep: blocks [0,320) pack weights into MFMA B-frag order;
// blocks [320,385) compute Wc/bvec/cvec; blocks [385,4292) histogram j.
// All three are independent; fusing saves 2 dispatch round-trips.
// ---------------------------------------------------------------------------
__global__ void prep_kernel(const float* __restrict__ Wm1,
                            const float* __restrict__ Wm2,
                            const float* __restrict__ Wu1,
                            const float* __restrict__ Wu2,
                            const float* __restrict__ We2,
                            const float* __restrict__ be2,
                            const float* __restrict__ bm1,
                            const float* __restrict__ bu1,
                            const float* __restrict__ bu2,
                            const int* __restrict__ eidx,
                            f16* __restrict__ wp, f16* __restrict__ Wcp,
                            float* __restrict__ bvec, float* __restrict__ cvec,
                            int* __restrict__ hist) {
  const int b = blockIdx.x;
  const int tid = threadIdx.x;
  if (b < 320) {
    // ---- pack Wm1(K=256)@0, Wm2@32768, Wu1@49152, Wu2@65536 (f16 units):
    // idx = ((t*KS+s)*64+lane)*8+e -> W[k][n], k=s*32+(lane>>4)*8+e,
    // n=t*16+(lane&15).
    int p = b * 256 + tid;
    if (p >= 81920) return;
    const float* src; int K, off, q;
    if (p < 32768)      { src = Wm1; K = 256; off = 0;     q = p; }
    else if (p < 49152) { src = Wm2; K = 128; off = 32768; q = p - 32768; }
    else if (p < 65536) { src = Wu1; K = 128; off = 49152; q = p - 49152; }
    else                { src = Wu2; K = 128; off = 65536; q = p - 65536; }
    int KS = K >> 5;
    int t   = q / (KS * 512);
    int rem = q - t * KS * 512;
    int s   = rem >> 9;
    int qq  = rem & 511;
    int lane = qq >> 3, e = qq & 7;
    int k = s * 32 + ((lane >> 4) << 3) + e;
    int n = (t << 4) + (lane & 15);
    wp[off + q] = (f16)src[k * HN + n];
  } else if (b < 385) {
    int bb = b - 320;
    if (bb < 64) {
      // ---- Wc = We2 @ Wm1_bot, written in packed B-frag layout (KS=4).
      int o = bb * 256 + tid;
      int k = o >> 7, n = o & 127;
      float s = 0.0f;
      for (int m = 0; m < 128; m++)
        s += We2[k * HN + m] * Wm1[(128 + m) * HN + n];
      int t = n >> 4, sg = k >> 5;
      int lane = (((k >> 3) & 3) << 4) | (n & 15);
      int e = k & 7;
      Wcp[((size_t)(t * 4 + sg) * 64 + lane) * 8 + e] = (f16)s;
    } else {
      // ---- bvec = bm1 + be2 @ Wm1_bot ; cvec = silu(bu1) @ Wu2 + bu2.
      if (tid < 128) {
        float s = bm1[tid];
        for (int m = 0; m < 128; m++) s += be2[m] * Wm1[(128 + m) * HN + tid];
        bvec[tid] = s;
      } else {
        int n = tid - 128;
        float s = bu2[n];
        for (int m = 0; m < 128; m++) s += silu_f(bu1[m]) * Wu2[m * HN + n];
        cvec[n] = s;
      }
    }
  } else {
    // ---- destination histogram (bin = j - NN).
    int e = (b - 385) * 256 + tid;
    if (e < EE) atomicAdd(&hist[eidx[EE + e] - NN], 1);
  }
}

// Single-block exclusive scan of 32768 bins -> cursor.
__global__ __launch_bounds__(1024) void scan_kernel(const int* __restrict__ hist,
                                                    int* __restrict__ cursor) {
  __shared__ int sbuf[1024];
  int tid = threadIdx.x;
  int base = tid * 32;
  int v[32];
  int s = 0;
#pragma unroll
  for (int k = 0; k < 32; k++) { int t = hist[base + k]; v[k] = s; s += t; }
  int tot = s;
  sbuf[tid] = s;
  __syncthreads();
  for (int off = 1; off < 1024; off <<= 1) {
    int x = (tid >= off) ? sbuf[tid - off] : 0;
    __syncthreads();
    sbuf[tid] += x;
    __syncthreads();
  }
  int excl = sbuf[tid] - tot;
#pragma unroll
  for (int k = 0; k < 32; k++) cursor[base + k] = excl + v[k];
}

// Build destination-sorted (i, j) pairs.
__global__ void reorder_kernel(const int* __restrict__ eidx,
                               int* __restrict__ cursor, int2* __restrict__ sij) {
  int e = blockIdx.x * 256 + threadIdx.x;
  if (e < EE) {
    int j = eidx[EE + e];
    int p = atomicAdd(&cursor[j - NN], 1);
    sij[p] = make_int2(eidx[e], j);
  }
}

// ---------------------------------------------------------------------------
// Ynode[i] = emb[i] @ Wm1_top + bvec  (f16 out, row-major [NN][128]).
// ---------------------------------------------------------------------------
__global__ __launch_bounds__(256, 2) void ynode_kernel(
    const float* __restrict__ emb, const f16* __restrict__ Wm1p,
    const float* __restrict__ bvec, f16* __restrict__ Ynode) {
  __shared__ __align__(16) f16 A1[TE * HN];
  const int tid = threadIdx.x;
  const int rbase = blockIdx.x * TE;

  for (int idx = tid; idx < TE * HN; idx += 256) {
    int e = idx >> 7, h = idx & (HN - 1);
    int row = rbase + e;
    float v = (row < NN) ? emb[(size_t)row * HN + h] : 0.0f;
    A1[swz_h(e, h)] = (f16)v;
  }
  __syncthreads();

  const int lane = tid & 63;
  const int w = tid >> 6;
  const int lr_ = lane & 15;
  const int hi = lane >> 4;
  const int r0w = w * 32;

  f16x8 a[2][4];
#pragma unroll
  for (int mt = 0; mt < 2; mt++)
#pragma unroll
    for (int s = 0; s < 4; s++)
      a[mt][s] = *(const f16x8*)(A1 + swz_h(r0w + mt * 16 + lr_, s * 32 + hi * 8));

  f32x4 acc[2][8];
#pragma unroll
  for (int t = 0; t < 8; t++) {
    float bv = bvec[t * 16 + lr_];
    acc[0][t] = (f32x4){bv, bv, bv, bv};
    acc[1][t] = (f32x4){bv, bv, bv, bv};
  }
#pragma unroll
  for (int t = 0; t < 8; t++)
#pragma unroll
    for (int s = 0; s < 4; s++) {  // top half of K=256 pack: s in 0..3
      f16x8 b = *(const f16x8*)(Wm1p + (size_t)((t * 8 + s) * 64 + lane) * 8);
      acc[0][t] = mfma16(a[0][s], b, acc[0][t]);
      acc[1][t] = mfma16(a[1][s], b, acc[1][t]);
    }
#pragma unroll
  for (int mt = 0; mt < 2; mt++)
#pragma unroll
    for (int t = 0; t < 8; t++)
#pragma unroll
      for (int r = 0; r < 4; r++) {
        int row = rbase + r0w + mt * 16 + hi * 4 + r;
        if (row < NN)
          Ynode[(size_t)row * HN + t * 16 + lr_] = (f16)acc[mt][t][r];
      }
}

// ---------------------------------------------------------------------------
// Edge kernel (destination-sorted): gather+rotate -> h1 in A-frag registers
// -> ONE GEMM (h1 @ Wc) -> mh = silu(z + Ynode[i]) finished IN C-REGS ->
// segmented run-merge scatter (bare ds_read+cmp+add loop, one atomic/run).
// launch_bounds(256,4): LDS 4x37.4KB=149.5KB<=160KB, VGPR 84<=128 budget.
// ---------------------------------------------------------------------------
__global__ __launch_bounds__(256, 4) void edge_kernel(
    const f16* __restrict__ Ynode, const float* __restrict__ npos,
    const float* __restrict__ gpos, const float* __restrict__ frames,
    const int* __restrict__ batch, const int2* __restrict__ sij,
    const float* __restrict__ We1, const float* __restrict__ be1,
    const f16* __restrict__ Wcp, float* __restrict__ out) {
  __shared__ __align__(16) float M[TE * 64];   // 32 KB scatter staging
  __shared__ float sW[4 * HN];                 // We1 rows (3x128) + be1
  __shared__ float sLR[TE * 3];
  __shared__ int sI[TE];
  __shared__ int sJ[TE];

  const int tid = threadIdx.x;
  const int ebase = blockIdx.x * TE;

  for (int k = tid; k < 4 * HN; k += 256)
    sW[k] = (k < 3 * HN) ? We1[k] : be1[k - 3 * HN];

  if (tid < TE) {
    int p = ebase + tid;
    bool valid = p < EE;
    int2 ij = sij[valid ? p : 0];
    int i = ij.x;
    int g = ij.y - NN;
    float r0 = gpos[g * 3 + 0] - npos[i * 3 + 0];
    float r1 = gpos[g * 3 + 1] - npos[i * 3 + 1];
    float r2 = gpos[g * 3 + 2] - npos[i * 3 + 2];
    const float* F = frames + batch[i] * 9;
    sLR[tid * 3 + 0] = F[0] * r0 + F[1] * r1 + F[2] * r2;
    sLR[tid * 3 + 1] = F[3] * r0 + F[4] * r1 + F[5] * r2;
    sLR[tid * 3 + 2] = F[6] * r0 + F[7] * r1 + F[8] * r2;
    sI[tid] = i;
    sJ[tid] = valid ? ij.y : -1;
  }
  __syncthreads();

  const int lane = tid & 63;
  const int w = tid >> 6;
  const int lr_ = lane & 15;
  const int hi = lane >> 4;
  const int r0w = w * 32;

  // h1 in A-frag registers: row=lr_(+16 for mt=1), k=s*32+hi*8+e.
  // Loop order (s,e) outer / mt inner: 4 LDS reads serve BOTH mt rows.
  const int row0 = r0w + lr_, row1 = r0w + 16 + lr_;
  const float l00 = sLR[row0 * 3], l01 = sLR[row0 * 3 + 1], l02 = sLR[row0 * 3 + 2];
  const float l10 = sLR[row1 * 3], l11 = sLR[row1 * 3 + 1], l12 = sLR[row1 * 3 + 2];
  f16x8 afr[2][4];
#pragma unroll
  for (int s = 0; s < 4; s++) {
    f16x8 a0, a1;
#pragma unroll
    for (int e = 0; e < 8; e++) {
      int k = s * 32 + hi * 8 + e;
      float w0 = sW[k], w1 = sW[HN + k], w2 = sW[2 * HN + k], wb = sW[3 * HN + k];
      a0[e] = (f16)silu_f(fmaf(l02, w2, fmaf(l01, w1, fmaf(l00, w0, wb))));
      a1[e] = (f16)silu_f(fmaf(l12, w2, fmaf(l11, w1, fmaf(l10, w0, wb))));
    }
    afr[0][s] = a0; afr[1][s] = a1;
  }

  f32x4 acc[2][8];
#pragma unroll
  for (int mt = 0; mt < 2; mt++)
#pragma unroll
    for (int t = 0; t < 8; t++) acc[mt][t] = (f32x4){0.f, 0.f, 0.f, 0.f};
#pragma unroll
  for (int t = 0; t < 8; t++)
#pragma unroll
    for (int s = 0; s < 4; s++) {
      f16x8 b = *(const f16x8*)(Wcp + (size_t)((t * 4 + s) * 64 + lane) * 8);
      acc[0][t] = mfma16(afr[0][s], b, acc[0][t]);
      acc[1][t] = mfma16(afr[1][s], b, acc[1][t]);
    }

  // Finish mh = silu(z + Ynode[i]) directly in C-layout registers:
  // thread holds rows {r0w+mt*16+hi*4+r} x cols {t*16+lr_}.
  #pragma unroll
  for (int mt = 0; mt < 2; mt++)
#pragma unroll
    for (int r = 0; r < 4; r++) {
      int row = r0w + mt * 16 + hi * 4 + r;
      const f16* yp = Ynode + (size_t)sI[row] * HN + lr_;
#pragma unroll
      for (int t = 0; t < 8; t++)
        acc[mt][t][r] = silu_f(acc[mt][t][r] + (float)yp[t * 16]);
    }

  // Segmented scatter: per half, transpose mh through LDS; run-merge
  // equal-j rows (sorted => ascending), one atomicAdd per run.
#pragma unroll
  for (int half = 0; half < 2; half++) {
    if (half) __syncthreads();
#pragma unroll
    for (int mt = 0; mt < 2; mt++)
#pragma unroll
      for (int tq = 0; tq < 4; tq++)
#pragma unroll
        for (int r = 0; r < 4; r++)
          M[swz_f(r0w + mt * 16 + hi * 4 + r, tq * 16 + lr_)] =
              acc[mt][half * 4 + tq][r];
    __syncthreads();
    const int colg = half * 64 + lane;
    float run = 0.0f;
    int jcur = -2;
#pragma unroll
    for (int k = 0; k < 32; k++) {
      int row = r0w + k;
      int jr = sJ[row];
      float v = M[swz_f(row, lane)];
      if (jr != jcur) {
        if (jcur >= 0) atomicAdd(&out[(size_t)jcur * HN + colg], run);
        run = 0.0f;
        jcur = jr;
      }
      if (jr >= 0) run += v;
    }
    if (jcur >= 0) atomicAdd(&out[(size_t)jcur * HN + colg], run);
  }
}

// ---------------------------------------------------------------------------
// Finalize (grid rows): mean_mh = seg_sum/max(cnt,1);
// x = mean_mh@Wm2 + bm2*(cnt>0); out = silu(x@Wu1+bu1)@Wu2+bu2, in place.
// Tail: each block also broadcast-fills a slice of node rows with cvec.
// ---------------------------------------------------------------------------
__global__ __launch_bounds__(256, 2) void finalize_kernel(
    float* __restrict__ out, const int* __restrict__ hist,
    const f16* __restrict__ Wm2p, const float* __restrict__ bm2,
    const f16* __restrict__ Wu1p, const float* __restrict__ bu1,
    const f16* __restrict__ Wu2p, const float* __restrict__ bu2,
    const float* __restrict__ cvec) {
  __shared__ __align__(16) f16 A1[TE * HN];
  __shared__ float sb[TE];   // per-row (cnt>0) flag
  const int tid = threadIdx.x;
  const int rbase = NN + blockIdx.x * TE;   // 256 blocks cover GG exactly

  for (int idx = tid; idx < TE * HN; idx += 256) {
    int e = idx >> 7, h = idx & (HN - 1);
    int c = hist[rbase + e - NN];
    float v = out[(size_t)(rbase + e) * HN + h] / fmaxf((float)c, 1.0f);
    A1[swz_h(e, h)] = (f16)v;
    if (h == 0) sb[e] = (c > 0) ? 1.0f : 0.0f;
  }
  __syncthreads();

  const int lane = tid & 63;
  const int w = tid >> 6;
  const int lr_ = lane & 15;
  const int hi = lane >> 4;
  const int r0w = w * 32;

  f32x4 acc[2][8];

  // G1: x = mean_mh @ Wm2 + bm2*flag
  {
    f16x8 a[2][4];
#pragma unroll
    for (int mt = 0; mt < 2; mt++)
#pragma unroll
      for (int s = 0; s < 4; s++)
        a[mt][s] = *(const f16x8*)(A1 + swz_h(r0w + mt * 16 + lr_, s * 32 + hi * 8));
#pragma unroll
    for (int mt = 0; mt < 2; mt++)
#pragma unroll
      for (int t = 0; t < 8; t++) {
        float bb = bm2[t * 16 + lr_];
        f32x4 c;
#pragma unroll
        for (int r = 0; r < 4; r++) c[r] = bb * sb[r0w + mt * 16 + hi * 4 + r];
        acc[mt][t] = c;
      }
#pragma unroll
    for (int t = 0; t < 8; t++)
#pragma unroll
      for (int s = 0; s < 4; s++) {
        f16x8 b = *(const f16x8*)(Wm2p + (size_t)((t * 4 + s) * 64 + lane) * 8);
        acc[0][t] = mfma16(a[0][s], b, acc[0][t]);
        acc[1][t] = mfma16(a[1][s], b, acc[1][t]);
      }
  }
  __syncthreads();
#pragma unroll
  for (int mt = 0; mt < 2; mt++)
#pragma unroll
    for (int t = 0; t < 8; t++)
#pragma unroll
      for (int r = 0; r < 4; r++)
        A1[swz_h(r0w + mt * 16 + hi * 4 + r, t * 16 + lr_)] = (f16)acc[mt][t][r];
  __syncthreads();

  // G2: h = silu(x @ Wu1 + bu1)
  {
    f16x8 a[2][4];
#pragma unroll
    for (int mt = 0; mt < 2; mt++)
#pragma unroll
      for (int s = 0; s < 4; s++)
        a[mt][s] = *(const f16x8*)(A1 + swz_h(r0w + mt * 16 + lr_, s * 32 + hi * 8));
#pragma unroll
    for (int t = 0; t < 8; t++) {
      float bv = bu1[t * 16 + lr_];
      acc[0][t] = (f32x4){bv, bv, bv, bv};
      acc[1][t] = (f32x4){bv, bv, bv, bv};
    }
#pragma unroll
    for (int t = 0; t < 8; t++)
#pragma unroll
      for (int s = 0; s < 4; s++) {
        f16x8 b = *(const f16x8*)(Wu1p + (size_t)((t * 4 + s) * 64 + lane) * 8);
        acc[0][t] = mfma16(a[0][s], b, acc[0][t]);
        acc[1][t] = mfma16(a[1][s], b, acc[1][t]);
      }
  }
  __syncthreads();
#pragma unroll
  for (int mt = 0; mt < 2; mt++)
#pragma unroll
    for (int t = 0; t < 8; t++)
#pragma unroll
      for (int r = 0; r < 4; r++)
        A1[swz_h(r0w + mt * 16 + hi * 4 + r, t * 16 + lr_)] = (f16)silu_f(acc[mt][t][r]);
  __syncthreads();

  // G3: out = h @ Wu2 + bu2
  {
    f16x8 a[2][4];
#pragma unroll
    for (int mt = 0; mt < 2; mt++)
#pragma unroll
      for (int s = 0; s < 4; s++)
        a[mt][s] = *(const f16x8*)(A1 + swz_h(r0w + mt * 16 + lr_, s * 32 + hi * 8));
#pragma unroll
    for (int t = 0; t < 8; t++) {
      float bv = bu2[t * 16 + lr_];
      acc[0][t] = (f32x4){bv, bv, bv, bv};
      acc[1][t] = (f32x4){bv, bv, bv, bv};
    }
#pragma unroll
    for (int t = 0; t < 8; t++)
#pragma unroll
      for (int s = 0; s < 4; s++) {
        f16x8 b = *(const f16x8*)(Wu2p + (size_t)((t * 4 + s) * 64 + lane) * 8);
        acc[0][t] = mfma16(a[0][s], b, acc[0][t]);
        acc[1][t] = mfma16(a[1][s], b, acc[1][t]);
      }
  }
#pragma unroll
  for (int mt = 0; mt < 2; mt++)
#pragma unroll
    for (int t = 0; t < 8; t++)
#pragma unroll
      for (int r = 0; r < 4; r++) {
        int row = rbase + r0w + mt * 16 + hi * 4 + r;
        out[(size_t)row * HN + t * 16 + lr_] = acc[mt][t][r];
      }

  // Node rows [0,NN): all equal cvec (mean is 0 there -> _mlp(0)).
  // Grid-stride over NN*HN/4 float4s across the 256 blocks.
  for (int i = blockIdx.x * 256 + tid; i < NN * HN / 4; i += 256 * 256) {
    float4 v = reinterpret_cast<const float4*>(cvec)[i & 31];
    reinterpret_cast<float4*>(out)[i] = v;
  }
}

extern "C" void kernel_launch(void* const* d_in, const int* in_sizes, int n_in,
                              void* d_out, int out_size, void* d_ws, size_t ws_size,
                              hipStream_t stream) {
  const float* emb    = (const float*)d_in[0];
  const float* npos   = (const float*)d_in[1];
  const float* gpos   = (const float*)d_in[2];
  const int*   eidx   = (const int*)d_in[3];
  const float* frames = (const float*)d_in[4];
  const int*   batch  = (const int*)d_in[5];
  const float* We1 = (const float*)d_in[6];
  const float* be1 = (const float*)d_in[7];
  const float* We2 = (const float*)d_in[8];
  const float* be2 = (const float*)d_in[9];
  const float* Wm1 = (const float*)d_in[10];
  const float* bm1 = (const float*)d_in[11];
  const float* Wm2 = (const float*)d_in[12];
  const float* bm2 = (const float*)d_in[13];
  const float* Wu1 = (const float*)d_in[14];
  const float* bu1 = (const float*)d_in[15];
  const float* Wu2 = (const float*)d_in[16];
  const float* bu2 = (const float*)d_in[17];

  float* out  = (float*)d_out;
  char* ws    = (char*)d_ws;
  int* hist   = (int*)ws;                        // 128 KB @ 0
  int* cursor = (int*)(ws + 131072);             // 128 KB
  f16* wp     = (f16*)(ws + 262144);             // 160 KB packed weights
  f16* Wm1p   = wp;                              // KS=8
  f16* Wm2p   = wp + 32768;
  f16* Wu1p   = wp + 49152;
  f16* Wu2p   = wp + 65536;
  f16* Wcp    = (f16*)(ws + 425984);             // 32 KB
  float* bvec = (float*)(ws + 458752);           // 512 B
  float* cvec = (float*)(ws + 459264);           // 512 B
  int2* sij   = (int2*)(ws + 524288);            // 8 MB sorted (i,j)
  f16* Ynode  = (f16*)(ws + 8524288);            // 5 MB

  // Zero only the grid-row region (edge scatter targets) + histogram.
  hipMemsetAsync(out + (size_t)NN * HN, 0, (size_t)GG * HN * sizeof(float), stream);
  hipMemsetAsync(hist, 0, (size_t)GG * sizeof(int), stream);

  int hb = (EE + 255) / 256;                     // 3907
  prep_kernel<<<385 + hb, 256, 0, stream>>>(
      Wm1, Wm2, Wu1, Wu2, We2, be2, bm1, bu1, bu2, eidx,
      wp, Wcp, bvec, cvec, hist);

  scan_kernel<<<1, 1024, 0, stream>>>(hist, cursor);
  reorder_kernel<<<hb, 256, 0, stream>>>(eidx, cursor, sij);
  ynode_kernel<<<(NN + TE - 1) / TE, 256, 0, stream>>>(emb, Wm1p, bvec, Ynode);

  int eblocks = (EE + TE - 1) / TE;              // 7813
  edge_kernel<<<eblocks, 256, 0, stream>>>(
      Ynode, npos, gpos, frames, batch, sij, We1, be1, Wcp, out);

  finalize_kernel<<<GG / TE, 256, 0, stream>>>(out, hist, Wm2p, bm2,
                                               Wu1p, bu1, Wu2p, bu2, cvec);
}